// Round 11
// baseline (104.219 us; speedup 1.0000x reference)
//
#include <hip/hip_runtime.h>
#include <float.h>

#define BATCH 2
#define SEQ   2048
#define HEADS 8
#define DHEAD 64
#define DIMM  512
#define NQKV  1536
#define QSCALE_L2 (0.125f * 1.44269504f)   // fold log2(e)*scale into Q (exp2 softmax)

#define QKV_ELEMS ((size_t)BATCH * HEADS * SEQ * DHEAD)   // 2097152
#define BHS (BATCH * HEADS * SEQ)                          // 32768
#define NSPLIT 4

typedef __bf16 bf16x8 __attribute__((ext_vector_type(8)));
typedef float  f32x4  __attribute__((ext_vector_type(4)));

#if __has_builtin(__builtin_amdgcn_exp2f)
#define EXP2F __builtin_amdgcn_exp2f
#else
#define EXP2F exp2f
#endif

__device__ __forceinline__ unsigned short bfbits(float f) {
  __bf16 h = (__bf16)f;
  return *(unsigned short*)&h;
}
__device__ __forceinline__ float bf2f(unsigned short u) {
  return __uint_as_float((unsigned)u << 16);
}
__device__ __forceinline__ unsigned cvtpk(float a, float b) {
  unsigned r;
  asm("v_cvt_pk_bf16_f32 %0, %1, %2" : "=v"(r) : "v"(a), "v"(b));
  return r;
}

// ---------------- fused prep: W transposes | mask sniff ----------------------
__device__ __forceinline__ void transpose_tile_dev(
    const float* __restrict__ W, unsigned short* __restrict__ Wt,
    int K, int N, int n0, int k0, int t, float T[64][65]) {
  {
    int r0 = t >> 4, c4 = t & 15;
#pragma unroll
    for (int rr = 0; rr < 4; ++rr) {
      int r = r0 + rr * 16;
      float4 v = *(const float4*)(W + (size_t)(k0 + r) * N + n0 + c4 * 4);
      T[r][c4 * 4 + 0] = v.x; T[r][c4 * 4 + 1] = v.y;
      T[r][c4 * 4 + 2] = v.z; T[r][c4 * 4 + 3] = v.w;
    }
  }
  __syncthreads();
  {
    int n = t >> 2, kc = t & 3;
    union { unsigned short u[16]; int4 v[2]; } p;
#pragma unroll
    for (int i = 0; i < 16; ++i) p.u[i] = bfbits(T[kc * 16 + i][n]);
    int4* dst = (int4*)(Wt + (size_t)(n0 + n) * K + k0 + kc * 16);
    dst[0] = p.v[0]; dst[1] = p.v[1];
  }
}

__global__ __launch_bounds__(256) void prep_all(
    const void* __restrict__ mraw,
    const float* __restrict__ Wqkv, const float* __restrict__ Wout,
    float* __restrict__ maskf,
    unsigned short* __restrict__ Wtq, unsigned short* __restrict__ Wto,
    unsigned* __restrict__ kmaxn) {
  __shared__ float T[64][65];
  __shared__ int f_bf16, f_f32, f_gt1, f_oddnz;
  const int b = blockIdx.x;
  const int t = threadIdx.x;
  if (b < 192) {                       // Wqkv transpose: 24 n-tiles x 8 k-tiles
    transpose_tile_dev(Wqkv, Wtq, DIMM, NQKV, (b % 24) * 64, (b / 24) * 64, t, T);
  } else if (b < 256) {                // Wout transpose: 8 x 8
    int c = b - 192;
    transpose_tile_dev(Wout, Wto, DIMM, DIMM, (c & 7) * 64, (c >> 3) * 64, t, T);
  } else {                             // mask sniff + normalize + kmaxn init
    if (t < 16) kmaxn[t] = 0u;
    if (t == 0) { f_bf16 = 0; f_f32 = 0; f_gt1 = 0; f_oddnz = 0; }
    __syncthreads();
    const unsigned int* w = (const unsigned int*)mraw;
    unsigned int v = w[t];             // first 1KB: safe for every candidate dtype
    if (v == 0x3f803f80u) f_bf16 = 1;
    if (v == 0x3f800000u) f_f32 = 1;
    if (v > 1u)           f_gt1 = 1;
    if ((t & 1) && v != 0u) f_oddnz = 1;
    __syncthreads();
    int mode;                          // 0=i32 1=u8 2=i64 3=f32 4=bf16
    if (f_bf16)       mode = 4;
    else if (f_f32)   mode = 3;
    else if (f_gt1)   mode = 1;
    else if (!f_oddnz) mode = 2;
    else              mode = 0;
    for (int i = t; i < BATCH * SEQ; i += 256) {
      bool keep;
      if (mode == 4)      keep = ((const unsigned short*)mraw)[i] != 0;
      else if (mode == 3) keep = ((const float*)mraw)[i] != 0.f;
      else if (mode == 1) keep = ((const unsigned char*)mraw)[i] != 0;
      else if (mode == 2) keep = w[2 * i] != 0u;
      else                keep = w[i] != 0u;
      maskf[i] = keep ? 1.f : 0.f;
    }
  }
}

// ---------------- qkv GEMM (MFMA) + fused per-(b,h) max|k| -------------------
// A staged from fp32 X with inline bf16 convert. Q/K epilogue: LDS repack ->
// coalesced dwordx4 stores.
__global__ __launch_bounds__(256) void gemm_qkv_mfma(
    const float* __restrict__ X, const unsigned short* __restrict__ Wt,
    unsigned short* __restrict__ Qbf, unsigned short* __restrict__ Kbf,
    unsigned short* __restrict__ Vt, unsigned* __restrict__ kmaxn) {
  __shared__ __align__(16) unsigned char Al[128 * 128];
  __shared__ __align__(16) unsigned char Bl[64 * 128];
  const int tid = threadIdx.x;
  const int lane = tid & 63;
  const int w = tid >> 6;
  const int l15 = lane & 15, g = lane >> 4;
  const int wr = w >> 1, wc = w & 1;
  int bid = blockIdx.x;                    // 768 blocks, bijective XCD swizzle
  int lid = (bid & 7) * 96 + (bid >> 3);
  int by = lid / 24, bx = lid - by * 24;   // by 0..31, bx 0..23
  const int m0 = by * 128;

  f32x4 acc[4][2] = {};
  const int srow = tid >> 3, scg = tid & 7;
  const int rsw = (l15 & 7) << 4;

  for (int k0 = 0; k0 < DIMM; k0 += 64) {
    __syncthreads();
#pragma unroll
    for (int it = 0; it < 4; ++it) {
      int row = srow + it * 32;
      int sw = (row & 7) << 4;
      const float* asrc = X + (size_t)(m0 + row) * DIMM + k0 + scg * 8;
      float4 a0 = *(const float4*)asrc;
      float4 a1 = *(const float4*)(asrc + 4);
      union { unsigned short u[8]; int4 v; } pk;
      pk.u[0] = bfbits(a0.x); pk.u[1] = bfbits(a0.y);
      pk.u[2] = bfbits(a0.z); pk.u[3] = bfbits(a0.w);
      pk.u[4] = bfbits(a1.x); pk.u[5] = bfbits(a1.y);
      pk.u[6] = bfbits(a1.z); pk.u[7] = bfbits(a1.w);
      *(int4*)(Al + row * 128 + ((scg * 16) ^ sw)) = pk.v;
      if (it < 2) {
        *(int4*)(Bl + row * 128 + ((scg * 16) ^ sw)) =
            *(const int4*)(Wt + (size_t)(bx * 64 + row) * DIMM + k0 + scg * 8);
      }
    }
    __syncthreads();
#pragma unroll
    for (int ks = 0; ks < 2; ++ks) {
      bf16x8 af[4], bfr[2];
#pragma unroll
      for (int mi = 0; mi < 4; ++mi)
        af[mi] = *(const bf16x8*)(Al + (wr * 64 + mi * 16 + l15) * 128 +
                                  ((ks * 64 + g * 16) ^ rsw));
#pragma unroll
      for (int nj = 0; nj < 2; ++nj)
        bfr[nj] = *(const bf16x8*)(Bl + (wc * 32 + nj * 16 + l15) * 128 +
                                   ((ks * 64 + g * 16) ^ rsw));
#pragma unroll
      for (int mi = 0; mi < 4; ++mi)
#pragma unroll
        for (int nj = 0; nj < 2; ++nj)
          acc[mi][nj] = __builtin_amdgcn_mfma_f32_16x16x32_bf16(
              af[mi], bfr[nj], acc[mi][nj], 0, 0, 0);
    }
  }
  const int chunk = bx >> 3;               // 0=Q 1=K 2=V
  const int bb = m0 >> 11;
  const int hh = bx & 7;                   // head (block covers exactly one)
  if (chunk == 2) {
#pragma unroll
    for (int nj = 0; nj < 2; ++nj) {
      int dd = wc * 32 + nj * 16 + l15;
#pragma unroll
      for (int mi = 0; mi < 4; ++mi) {
        int ii0 = (m0 & (SEQ - 1)) + wr * 64 + mi * 16 + g * 4;
        union { unsigned short u[4]; ushort4 v; } pk;
#pragma unroll
        for (int r = 0; r < 4; ++r) pk.u[r] = bfbits(acc[mi][nj][r]);
        *(ushort4*)(Vt + ((size_t)(bb * HEADS + hh) * DHEAD + dd) * SEQ + ii0) = pk.v;
      }
    }
  } else {
    if (chunk == 1) {                      // fused key-bound: max|k| per (b,h)
      float kab = 0.f;
#pragma unroll
      for (int nj = 0; nj < 2; ++nj)
#pragma unroll
        for (int mi = 0; mi < 4; ++mi)
#pragma unroll
          for (int r = 0; r < 4; ++r) kab = fmaxf(kab, fabsf(acc[mi][nj][r]));
#pragma unroll
      for (int d = 1; d < 64; d <<= 1) kab = fmaxf(kab, __shfl_xor(kab, d));
      if (lane == 0)
        atomicMax(kmaxn + (bb * HEADS + hh), __float_as_uint(kab * 1.005f));
    }
    // repack 128x64 bf16 tile through LDS -> coalesced stores
    unsigned short* dst = (chunk == 0) ? Qbf : Kbf;
    const float sc = (chunk == 0) ? QSCALE_L2 : 1.f;
    __syncthreads();                       // Al reuse
#pragma unroll
    for (int nj = 0; nj < 2; ++nj) {
      int dd = wc * 32 + nj * 16 + l15;
#pragma unroll
      for (int mi = 0; mi < 4; ++mi) {
#pragma unroll
        for (int r = 0; r < 4; ++r) {
          int rowl = wr * 64 + mi * 16 + g * 4 + r;
          *(unsigned short*)(Al + rowl * 128 + ((dd * 2) ^ ((rowl & 7) << 4))) =
              bfbits(acc[mi][nj][r] * sc);
        }
      }
    }
    __syncthreads();
    const int rr = tid >> 1, hf = tid & 1;
    const int ii0 = (m0 & (SEQ - 1));
    unsigned short* gout =
        dst + ((size_t)(bb * HEADS + hh) * SEQ + ii0 + rr) * DHEAD + hf * 32;
    const int sw2 = (rr & 7) << 4;
#pragma unroll
    for (int q = 0; q < 4; ++q)
      *(int4*)(gout + q * 8) =
          *(const int4*)(Al + rr * 128 + ((hf * 64 + q * 16) ^ sw2));
  }
}

// ---------------- flash attention: split-KV x4, 2 q-strips, full-rate PV -----
// S^T = mfma(K,Q): lane (l15,g) holds P[q=l15][key=16j+4g+r]. P quads are
// repacked through a wave-private LDS buffer (no barrier; in-order DS queue)
// into x32 A-fragments (keys 32G+8g..+7) so PV runs on mfma_16x16x32.
__global__ __launch_bounds__(256) void attn_split(const unsigned short* __restrict__ Qbf,
                                                  const unsigned short* __restrict__ Kbf,
                                                  const unsigned short* __restrict__ Vt,
                                                  const float* __restrict__ maskf,
                                                  const unsigned* __restrict__ kmaxn,
                                                  unsigned short* __restrict__ Po,
                                                  float* __restrict__ LSUM) {
  __shared__ __align__(16) unsigned char Ks[16384];   // 2 x 8KB dbuf
  __shared__ __align__(16) unsigned char Vs[16384];
  __shared__ __align__(16) unsigned char Ps[8192];    // 4 waves x 2KB private

  const int tid = threadIdx.x;
  const int lane = tid & 63;
  const int w = tid >> 6;
  const int l15 = lane & 15, g = lane >> 4;

  int fid = blockIdx.x;
  int lid = (fid & 7) * 128 + (fid >> 3);  // bijective over 1024
  const int bh = lid >> 6;                 // 0..15
  const int rem = lid & 63;
  const int qp = rem >> 2;                 // q-pair 0..15 (128 queries)
  const int quarter = rem & 3;
  const int bb = bh >> 3;

  const unsigned short* Qg = Qbf + ((size_t)bh * SEQ + qp * 128) * DHEAD;
  const unsigned short* Kg = Kbf + (size_t)bh * SEQ * DHEAD;
  const unsigned short* Vg = Vt  + (size_t)bh * DHEAD * SEQ;
  const float* mrow = maskf + bb * SEQ;

  bf16x8 qf0a, qf1a, qf0b, qf1b;
  {
    const unsigned char* qra = (const unsigned char*)(Qg + (size_t)(w * 16 + l15) * DHEAD);
    qf0a = *(const bf16x8*)(qra + g * 16);
    qf1a = *(const bf16x8*)(qra + 64 + g * 16);
    const unsigned char* qrb = qra + 64 * DHEAD * 2;
    qf0b = *(const bf16x8*)(qrb + g * 16);
    qf1b = *(const bf16x8*)(qrb + 64 + g * 16);
  }
  float Bxa, Bxb;
  {
    const float kabs = __uint_as_float(kmaxn[bh]);
    float qa = 0.f, qb2 = 0.f;
#pragma unroll
    for (int i = 0; i < 8; ++i) {
      float a0 = (float)qf0a[i]; qa += a0 * a0;
      float a1 = (float)qf1a[i]; qa += a1 * a1;
      float b0 = (float)qf0b[i]; qb2 += b0 * b0;
      float b1 = (float)qf1b[i]; qb2 += b1 * b1;
    }
    qa += __shfl_xor(qa, 16);  qa += __shfl_xor(qa, 32);
    qb2 += __shfl_xor(qb2, 16); qb2 += __shfl_xor(qb2, 32);
    Bxa = sqrtf(qa) * 8.f * kabs;          // log2-units (Q pre-scaled)
    Bxb = sqrtf(qb2) * 8.f * kabs;
  }

  f32x4 oa[4] = {}, ob[4] = {};
  float lsa = 0.f, lsb = 0.f;

  const int sm = tid >> 2;
  const int sc = (tid & 3) * 32;
  const int ssw = (sm & 7) << 4;
  const int rsw = (l15 & 7) << 4;
  const int kt0 = quarter * 8;
  unsigned char* Pw = Ps + w * 2048 + l15 * 128;   // wave-private P row

  int4 rk0, rk1, rv0, rv1;
  {
    const unsigned char* ksrc =
        (const unsigned char*)(Kg + (size_t)kt0 * 64 * DHEAD) + sm * 128 + sc;
    const unsigned char* vsrc =
        (const unsigned char*)(Vg + (size_t)sm * SEQ + kt0 * 64) + sc;
    rk0 = *(const int4*)(ksrc); rk1 = *(const int4*)(ksrc + 16);
    rv0 = *(const int4*)(vsrc); rv1 = *(const int4*)(vsrc + 16);
  }
  *(int4*)(Ks + sm * 128 + ((sc)      ^ ssw)) = rk0;
  *(int4*)(Ks + sm * 128 + ((sc + 16) ^ ssw)) = rk1;
  *(int4*)(Vs + sm * 128 + ((sc)      ^ ssw)) = rv0;
  *(int4*)(Vs + sm * 128 + ((sc + 16) ^ ssw)) = rv1;
  __syncthreads();

  for (int t = 0; t < 8; ++t) {
    const int kt = kt0 + t;
    const int co = (t & 1) << 13;          // current buffer byte offset
    const int no = co ^ 8192;              // next buffer
    float4 km[4];
#pragma unroll
    for (int j = 0; j < 4; ++j) km[j] = *(const float4*)(mrow + kt * 64 + 16 * j + 4 * g);
    if (t < 7) {                           // T14: issue next tile's loads now
      const unsigned char* ksrc =
          (const unsigned char*)(Kg + (size_t)(kt + 1) * 64 * DHEAD) + sm * 128 + sc;
      const unsigned char* vsrc =
          (const unsigned char*)(Vg + (size_t)sm * SEQ + (kt + 1) * 64) + sc;
      rk0 = *(const int4*)(ksrc); rk1 = *(const int4*)(ksrc + 16);
      rv0 = *(const int4*)(vsrc); rv1 = *(const int4*)(vsrc + 16);
    }

    // S^T = K · Q^T for both strips (K-frags read once)
    f32x4 sa[4], sb[4];
    __builtin_amdgcn_s_setprio(1);
#pragma unroll
    for (int j = 0; j < 4; ++j) {
      const unsigned char* krow = Ks + co + (16 * j + l15) * 128;
      bf16x8 kf0 = *(const bf16x8*)(krow + ((g * 16)      ^ rsw));
      bf16x8 kf1 = *(const bf16x8*)(krow + ((64 + g * 16) ^ rsw));
      f32x4 za = (f32x4){0.f, 0.f, 0.f, 0.f};
      za = __builtin_amdgcn_mfma_f32_16x16x32_bf16(kf0, qf0a, za, 0, 0, 0);
      za = __builtin_amdgcn_mfma_f32_16x16x32_bf16(kf1, qf1a, za, 0, 0, 0);
      sa[j] = za;
      f32x4 zb = (f32x4){0.f, 0.f, 0.f, 0.f};
      zb = __builtin_amdgcn_mfma_f32_16x16x32_bf16(kf0, qf0b, zb, 0, 0, 0);
      zb = __builtin_amdgcn_mfma_f32_16x16x32_bf16(kf1, qf1b, zb, 0, 0, 0);
      sb[j] = zb;
    }
    __builtin_amdgcn_s_setprio(0);

    // strip A: p = exp2(s - B) * km -> pack quads -> LDS repack -> x32 PV
    {
      uint2 pk[4];
#pragma unroll
      for (int j = 0; j < 4; ++j) {
        float p0 = EXP2F(sa[j][0] - Bxa) * km[j].x;
        float p1 = EXP2F(sa[j][1] - Bxa) * km[j].y;
        float p2 = EXP2F(sa[j][2] - Bxa) * km[j].z;
        float p3 = EXP2F(sa[j][3] - Bxa) * km[j].w;
        lsa += (p0 + p1) + (p2 + p3);
        pk[j].x = cvtpk(p0, p1);
        pk[j].y = cvtpk(p2, p3);
      }
#pragma unroll
      for (int j = 0; j < 4; ++j)
        *(uint2*)(Pw + ((32 * j + 8 * g) ^ rsw)) = pk[j];
      bf16x8 paf0 = *(const bf16x8*)(Pw + ((16 * g)      ^ rsw));
      bf16x8 paf1 = *(const bf16x8*)(Pw + ((64 + 16 * g) ^ rsw));
      __builtin_amdgcn_s_setprio(1);
#pragma unroll
      for (int dj = 0; dj < 4; ++dj) {
        const unsigned char* vrow = Vs + co + (16 * dj + l15) * 128;
        bf16x8 vb0 = *(const bf16x8*)(vrow + ((16 * g)      ^ rsw));
        bf16x8 vb1 = *(const bf16x8*)(vrow + ((64 + 16 * g) ^ rsw));
        oa[dj] = __builtin_amdgcn_mfma_f32_16x16x32_bf16(paf0, vb0, oa[dj], 0, 0, 0);
        oa[dj] = __builtin_amdgcn_mfma_f32_16x16x32_bf16(paf1, vb1, oa[dj], 0, 0, 0);
      }
      __builtin_amdgcn_s_setprio(0);
    }
    // strip B (reuses the same wave-private P buffer; DS ops are in-order)
    {
      uint2 pk[4];
#pragma unroll
      for (int j = 0; j < 4; ++j) {
        float p0 = EXP2F(sb[j][0] - Bxb) * km[j].x;
        float p1 = EXP2F(sb[j][1] - Bxb) * km[j].y;
        float p2 = EXP2F(sb[j][2] - Bxb) * km[j].z;
        float p3 = EXP2F(sb[j][3] - Bxb) * km[j].w;
        lsb += (p0 + p1) + (p2 + p3);
        pk[j].x = cvtpk(p0, p1);
        pk[j].y = cvtpk(p2, p3);
      }
#pragma unroll
      for (int j = 0; j < 4; ++j)
        *(uint2*)(Pw + ((32 * j + 8 * g) ^ rsw)) = pk[j];
      bf16x8 paf0 = *(const bf16x8*)(Pw + ((16 * g)      ^ rsw));
      bf16x8 paf1 = *(const bf16x8*)(Pw + ((64 + 16 * g) ^ rsw));
      __builtin_amdgcn_s_setprio(1);
#pragma unroll
      for (int dj = 0; dj < 4; ++dj) {
        const unsigned char* vrow = Vs + co + (16 * dj + l15) * 128;
        bf16x8 vb0 = *(const bf16x8*)(vrow + ((16 * g)      ^ rsw));
        bf16x8 vb1 = *(const bf16x8*)(vrow + ((64 + 16 * g) ^ rsw));
        ob[dj] = __builtin_amdgcn_mfma_f32_16x16x32_bf16(paf0, vb0, ob[dj], 0, 0, 0);
        ob[dj] = __builtin_amdgcn_mfma_f32_16x16x32_bf16(paf1, vb1, ob[dj], 0, 0, 0);
      }
      __builtin_amdgcn_s_setprio(0);
    }

    if (t < 7) {                           // stage next tile into other buffer
      *(int4*)(Ks + no + sm * 128 + ((sc)      ^ ssw)) = rk0;
      *(int4*)(Ks + no + sm * 128 + ((sc + 16) ^ ssw)) = rk1;
      *(int4*)(Vs + no + sm * 128 + ((sc)      ^ ssw)) = rv0;
      *(int4*)(Vs + no + sm * 128 + ((sc + 16) ^ ssw)) = rv1;
      __syncthreads();                     // single barrier per tile
    }
  }

  // epilogue: write unnormalized partial O + row-sums (shared B across splits)
#pragma unroll
  for (int r = 0; r < 4; ++r) {
    int rowa = qp * 128 + w * 16 + 4 * g + r;
    size_t basea = (size_t)quarter * QKV_ELEMS + ((size_t)bh * SEQ + rowa) * DHEAD + l15;
    Po[basea]      = bfbits(oa[0][r]);
    Po[basea + 16] = bfbits(oa[1][r]);
    Po[basea + 32] = bfbits(oa[2][r]);
    Po[basea + 48] = bfbits(oa[3][r]);
    size_t baseb = basea + (size_t)64 * DHEAD;
    Po[baseb]      = bfbits(ob[0][r]);
    Po[baseb + 16] = bfbits(ob[1][r]);
    Po[baseb + 32] = bfbits(ob[2][r]);
    Po[baseb + 48] = bfbits(ob[3][r]);
  }
  lsa += __shfl_xor(lsa, 16); lsa += __shfl_xor(lsa, 32);
  lsb += __shfl_xor(lsb, 16); lsb += __shfl_xor(lsb, 32);
  if (g == 0) {
    int rowa = qp * 128 + w * 16 + l15;
    LSUM[quarter * BHS + bh * SEQ + rowa] = lsa;
    LSUM[quarter * BHS + bh * SEQ + rowa + 64] = lsb;
  }
}

// ---------------- combine 4 partials (plain sum) + conv residual -> Obf ------
__global__ __launch_bounds__(256) void combine_conv(
    const unsigned short* __restrict__ Po, const float* __restrict__ LSUM,
    const unsigned short* __restrict__ Vt, const float* __restrict__ cw,
    unsigned short* __restrict__ Obf) {
  __shared__ float T[96][68];
  __shared__ float cwl[33];
  const int tid = threadIdx.x;
  const int bid = blockIdx.x;              // 512 = 16 bh x 32 n-chunks
  const int bh = bid >> 5;
  const int n0 = (bid & 31) * 64;
  const int hh = bh & 7;
  if (tid < 33) cwl[tid] = cw[hh * 33 + tid];
  for (int idx = tid; idx < 64 * 24; idx += 256) {
    int d = idx / 24, c4 = idx - (idx / 24) * 24;
    int nbase = n0 - 16 + c4 * 4;
    const unsigned short* src = Vt + ((size_t)bh * DHEAD + d) * SEQ;
#pragma unroll
    for (int q = 0; q < 4; ++q) {
      int n = nbase + q;
      T[c4 * 4 + q][d] = (n >= 0 && n < SEQ) ? bf2f(src[n]) : 0.f;
    }
  }
  __syncthreads();
#pragma unroll
  for (int p = 0; p < 4; ++p) {
    int n = (tid >> 4) + p * 16;           // 0..63
    int d4 = tid & 15;
    int row = bh * SEQ + n0 + n;
    float tot = 0.f;
#pragma unroll
    for (int q = 0; q < NSPLIT; ++q) tot += LSUM[q * BHS + row];
    float inv = (tot > 0.f) ? 1.f / tot : 0.f;
    float o0 = 0.f, o1 = 0.f, o2 = 0.f, o3 = 0.f;
#pragma unroll
    for (int q = 0; q < NSPLIT; ++q) {
      ushort4 a = *(const ushort4*)(Po + (size_t)q * QKV_ELEMS + (size_t)row * DHEAD + d4 * 4);
      o0 += bf2f(a.x); o1 += bf2f(a.y);
      o2 += bf2f(a.z); o3 += bf2f(a.w);
    }
    o0 *= inv; o1 *= inv; o2 *= inv; o3 *= inv;
#pragma unroll
    for (int t = 0; t < 33; ++t) {
      float wv = cwl[t];
      float4 tv = *(const float4*)&T[n + t][d4 * 4];
      o0 += wv * tv.x; o1 += wv * tv.y; o2 += wv * tv.z; o3 += wv * tv.w;
    }
    union { unsigned short u[4]; ushort4 v; } pk;
    pk.u[0] = bfbits(o0); pk.u[1] = bfbits(o1);
    pk.u[2] = bfbits(o2); pk.u[3] = bfbits(o3);
    *(ushort4*)(Obf + (size_t)row * DHEAD + d4 * 4) = pk.v;
  }
}

// ---------------- out GEMM (MFMA): Obf bf16 gather-A, 64x64 tiles ------------
__global__ __launch_bounds__(256) void gemm_out_mfma(
    const unsigned short* __restrict__ Obf, const unsigned short* __restrict__ Wt,
    const float* __restrict__ bias, const float* __restrict__ maskf,
    float* __restrict__ out) {
  __shared__ __align__(16) unsigned char Al[64 * 128];
  __shared__ __align__(16) unsigned char Bl[64 * 128];
  const int tid = threadIdx.x;
  const int lane = tid & 63;
  const int w = tid >> 6;
  const int l15 = lane & 15, g = lane >> 4;
  const int wr = w >> 1, wc = w & 1;
  int bid = blockIdx.x;                    // 512 blocks
  int lid = (bid & 7) * 64 + (bid >> 3);
  int by = lid >> 3, bx = lid & 7;         // by 0..63, bx 0..7
  const int m0 = by * 64, n0 = bx * 64;
  const int bb = m0 >> 11;
  const int ii0 = m0 & (SEQ - 1);

  f32x4 acc[2][2] = {};
  const int srow = tid >> 3, scg = tid & 7;
  const int rsw = (l15 & 7) << 4;

  for (int k0 = 0; k0 < DIMM; k0 += 64) {
    const int hh = k0 >> 6;
    __syncthreads();
#pragma unroll
    for (int it = 0; it < 2; ++it) {
      int row = srow + it * 32;
      int sw = (row & 7) << 4;
      *(int4*)(Al + row * 128 + ((scg * 16) ^ sw)) =
          *(const int4*)(Obf + ((size_t)(bb * HEADS + hh) * SEQ + ii0 + row) * DHEAD + scg * 8);
      *(int4*)(Bl + row * 128 + ((scg * 16) ^ sw)) =
          *(const int4*)(Wt + (size_t)(n0 + row) * DIMM + k0 + scg * 8);
    }
    __syncthreads();
#pragma unroll
    for (int ks = 0; ks < 2; ++ks) {
      bf16x8 af[2], bfr[2];
#pragma unroll
      for (int mi = 0; mi < 2; ++mi)
        af[mi] = *(const bf16x8*)(Al + (wr * 32 + mi * 16 + l15) * 128 +
                                  ((ks * 64 + g * 16) ^ rsw));
#pragma unroll
      for (int nj = 0; nj < 2; ++nj)
        bfr[nj] = *(const bf16x8*)(Bl + (wc * 32 + nj * 16 + l15) * 128 +
                                   ((ks * 64 + g * 16) ^ rsw));
#pragma unroll
      for (int mi = 0; mi < 2; ++mi)
#pragma unroll
        for (int nj = 0; nj < 2; ++nj)
          acc[mi][nj] = __builtin_amdgcn_mfma_f32_16x16x32_bf16(
              af[mi], bfr[nj], acc[mi][nj], 0, 0, 0);
    }
  }
#pragma unroll
  for (int nj = 0; nj < 2; ++nj) {
    int col = n0 + wc * 32 + nj * 16 + l15;
    float bcol = bias[col];
#pragma unroll
    for (int mi = 0; mi < 2; ++mi) {
#pragma unroll
      for (int r = 0; r < 4; ++r) {
        int m = m0 + wr * 32 + mi * 16 + g * 4 + r;
        out[(size_t)m * DIMM + col] = (acc[mi][nj][r] + bcol) * maskf[m];
      }
    }
  }
}

extern "C" void kernel_launch(void* const* d_in, const int* in_sizes, int n_in,
                              void* d_out, int out_size, void* d_ws, size_t ws_size,
                              hipStream_t stream) {
  const float* x     = (const float*)d_in[0];
  const void*  mask  = d_in[1];
  const float* Wqkv  = (const float*)d_in[2];
  const float* Wout  = (const float*)d_in[3];
  const float* bout  = (const float*)d_in[4];
  const float* convw = (const float*)d_in[5];
  float* out = (float*)d_out;

  float* maskf = (float*)d_ws;
  unsigned* kmaxn = (unsigned*)(maskf + 4096);           // 16 used, pad 64
  unsigned short* Qbf = (unsigned short*)(kmaxn + 64);
  unsigned short* Kbf = Qbf + QKV_ELEMS;
  unsigned short* Vt  = Kbf + QKV_ELEMS;
  unsigned short* Po  = Vt + QKV_ELEMS;                  // NSPLIT partials
  float* LSUM         = (float*)(Po + NSPLIT * QKV_ELEMS);
  unsigned short* Obf = (unsigned short*)(LSUM + NSPLIT * BHS);
  unsigned short* Wtq = Obf + QKV_ELEMS;                 // 1536*512
  unsigned short* Wto = Wtq + (size_t)NQKV * DIMM;       // 512*512

  prep_all<<<257, 256, 0, stream>>>(mask, Wqkv, Wout, maskf, Wtq, Wto, kmaxn);
  gemm_qkv_mfma<<<768, 256, 0, stream>>>(x, Wtq, Qbf, Kbf, Vt, kmaxn);
  attn_split<<<1024, 256, 0, stream>>>(Qbf, Kbf, Vt, maskf, kmaxn, Po, LSUM);
  combine_conv<<<512, 256, 0, stream>>>(Po, LSUM, Vt, convw, Obf);
  gemm_out_mfma<<<512, 256, 0, stream>>>(Obf, Wto, bout, maskf, out);
}

// Round 12
// 98.334 us; speedup vs baseline: 1.0598x; 1.0598x over previous
//
#include <hip/hip_runtime.h>
#include <float.h>

#define BATCH 2
#define SEQ   2048
#define HEADS 8
#define DHEAD 64
#define DIMM  512
#define NQKV  1536
#define QSCALE_L2 (0.125f * 1.44269504f)   // fold log2(e)*scale into Q (exp2 softmax)

#define QKV_ELEMS ((size_t)BATCH * HEADS * SEQ * DHEAD)   // 2097152
#define BHS (BATCH * HEADS * SEQ)                          // 32768
#define NSPLIT 2

typedef __bf16 bf16x8 __attribute__((ext_vector_type(8)));
typedef short  s16x4  __attribute__((ext_vector_type(4)));
typedef float  f32x4  __attribute__((ext_vector_type(4)));

#if __has_builtin(__builtin_amdgcn_exp2f)
#define EXP2F __builtin_amdgcn_exp2f
#else
#define EXP2F exp2f
#endif

__device__ __forceinline__ unsigned short bfbits(float f) {
  __bf16 h = (__bf16)f;
  return *(unsigned short*)&h;
}
__device__ __forceinline__ float bf2f(unsigned short u) {
  return __uint_as_float((unsigned)u << 16);
}
__device__ __forceinline__ unsigned cvtpk(float a, float b) {
  unsigned r;
  asm("v_cvt_pk_bf16_f32 %0, %1, %2" : "=v"(r) : "v"(a), "v"(b));
  return r;
}
__device__ __forceinline__ f32x4 mfma16(s16x4 a, s16x4 b, f32x4 c) {
#if __has_builtin(__builtin_amdgcn_mfma_f32_16x16x16bf16_1k)
  return __builtin_amdgcn_mfma_f32_16x16x16bf16_1k(a, b, c, 0, 0, 0);
#else
  f32x4 d;
  asm("v_mfma_f32_16x16x16_bf16 %0, %1, %2, %3" : "=v"(d) : "v"(a), "v"(b), "v"(c));
  return d;
#endif
}

// ---------------- fused prep: X->bf16 | W transposes | mask sniff ------------
__device__ __forceinline__ void transpose_tile_dev(
    const float* __restrict__ W, unsigned short* __restrict__ Wt,
    int K, int N, int n0, int k0, int t, float T[64][65]) {
  {
    int r0 = t >> 4, c4 = t & 15;
#pragma unroll
    for (int rr = 0; rr < 4; ++rr) {
      int r = r0 + rr * 16;
      float4 v = *(const float4*)(W + (size_t)(k0 + r) * N + n0 + c4 * 4);
      T[r][c4 * 4 + 0] = v.x; T[r][c4 * 4 + 1] = v.y;
      T[r][c4 * 4 + 2] = v.z; T[r][c4 * 4 + 3] = v.w;
    }
  }
  __syncthreads();
  {
    int n = t >> 2, kc = t & 3;
    union { unsigned short u[16]; int4 v[2]; } p;
#pragma unroll
    for (int i = 0; i < 16; ++i) p.u[i] = bfbits(T[kc * 16 + i][n]);
    int4* dst = (int4*)(Wt + (size_t)(n0 + n) * K + k0 + kc * 16);
    dst[0] = p.v[0]; dst[1] = p.v[1];
  }
}

__global__ __launch_bounds__(256) void prep_all(
    const float* __restrict__ X, const void* __restrict__ mraw,
    const float* __restrict__ Wqkv, const float* __restrict__ Wout,
    unsigned short* __restrict__ Xbf, float* __restrict__ maskf,
    unsigned short* __restrict__ Wtq, unsigned short* __restrict__ Wto,
    unsigned* __restrict__ kmaxn) {
  __shared__ float T[64][65];
  __shared__ int f_bf16, f_f32, f_gt1, f_oddnz;
  const int b = blockIdx.x;
  const int t = threadIdx.x;
  if (b < 1024) {                      // X fp32 -> bf16 (2M elems)
    size_t i = ((size_t)b * 256 + t) * 8;
    float4 a0 = *(const float4*)(X + i);
    float4 a1 = *(const float4*)(X + i + 4);
    union { unsigned short u[8]; int4 v; } pk;
    pk.u[0] = bfbits(a0.x); pk.u[1] = bfbits(a0.y);
    pk.u[2] = bfbits(a0.z); pk.u[3] = bfbits(a0.w);
    pk.u[4] = bfbits(a1.x); pk.u[5] = bfbits(a1.y);
    pk.u[6] = bfbits(a1.z); pk.u[7] = bfbits(a1.w);
    *(int4*)(Xbf + i) = pk.v;
  } else if (b < 1216) {               // Wqkv transpose: 24 n-tiles x 8 k-tiles
    int bb2 = b - 1024;
    transpose_tile_dev(Wqkv, Wtq, DIMM, NQKV, (bb2 % 24) * 64, (bb2 / 24) * 64, t, T);
  } else if (b < 1280) {               // Wout transpose: 8 x 8
    int bb2 = b - 1216;
    transpose_tile_dev(Wout, Wto, DIMM, DIMM, (bb2 & 7) * 64, (bb2 >> 3) * 64, t, T);
  } else {                             // mask sniff + normalize + kmaxn init
    if (t < 16) kmaxn[t] = 0u;
    if (t == 0) { f_bf16 = 0; f_f32 = 0; f_gt1 = 0; f_oddnz = 0; }
    __syncthreads();
    const unsigned int* w = (const unsigned int*)mraw;
    unsigned int v = w[t];             // first 1KB: safe for every candidate dtype
    if (v == 0x3f803f80u) f_bf16 = 1;
    if (v == 0x3f800000u) f_f32 = 1;
    if (v > 1u)           f_gt1 = 1;
    if ((t & 1) && v != 0u) f_oddnz = 1;
    __syncthreads();
    int mode;                          // 0=i32 1=u8 2=i64 3=f32 4=bf16
    if (f_bf16)       mode = 4;
    else if (f_f32)   mode = 3;
    else if (f_gt1)   mode = 1;
    else if (!f_oddnz) mode = 2;
    else              mode = 0;
    for (int i = t; i < BATCH * SEQ; i += 256) {
      bool keep;
      if (mode == 4)      keep = ((const unsigned short*)mraw)[i] != 0;
      else if (mode == 3) keep = ((const float*)mraw)[i] != 0.f;
      else if (mode == 1) keep = ((const unsigned char*)mraw)[i] != 0;
      else if (mode == 2) keep = w[2 * i] != 0u;
      else                keep = w[i] != 0u;
      maskf[i] = keep ? 1.f : 0.f;
    }
  }
}

// ---------------- qkv GEMM (MFMA) + fused per-(b,h) max|k| -------------------
// Q/K epilogue: repack through LDS -> coalesced dwordx4 stores.
__global__ __launch_bounds__(256) void gemm_qkv_mfma(
    const unsigned short* __restrict__ Xbf, const unsigned short* __restrict__ Wt,
    unsigned short* __restrict__ Qbf, unsigned short* __restrict__ Kbf,
    unsigned short* __restrict__ Vt, unsigned* __restrict__ kmaxn) {
  __shared__ __align__(16) unsigned char Al[128 * 128];
  __shared__ __align__(16) unsigned char Bl[64 * 128];
  const int tid = threadIdx.x;
  const int lane = tid & 63;
  const int w = tid >> 6;
  const int l15 = lane & 15, g = lane >> 4;
  const int wr = w >> 1, wc = w & 1;
  int bid = blockIdx.x;                    // 768 blocks, bijective XCD swizzle
  int lid = (bid & 7) * 96 + (bid >> 3);
  int by = lid / 24, bx = lid - by * 24;   // by 0..31, bx 0..23
  const int m0 = by * 128;

  f32x4 acc[4][2] = {};
  const int srow = tid >> 3, scg = tid & 7;
  const int rsw = (l15 & 7) << 4;

  for (int k0 = 0; k0 < DIMM; k0 += 64) {
    __syncthreads();
#pragma unroll
    for (int it = 0; it < 4; ++it) {
      int row = srow + it * 32;
      int sw = (row & 7) << 4;
      *(int4*)(Al + row * 128 + ((scg * 16) ^ sw)) =
          *(const int4*)(Xbf + (size_t)(m0 + row) * DIMM + k0 + scg * 8);
      if (it < 2) {
        *(int4*)(Bl + row * 128 + ((scg * 16) ^ sw)) =
            *(const int4*)(Wt + (size_t)(bx * 64 + row) * DIMM + k0 + scg * 8);
      }
    }
    __syncthreads();
#pragma unroll
    for (int ks = 0; ks < 2; ++ks) {
      bf16x8 af[4], bfr[2];
#pragma unroll
      for (int mi = 0; mi < 4; ++mi)
        af[mi] = *(const bf16x8*)(Al + (wr * 64 + mi * 16 + l15) * 128 +
                                  ((ks * 64 + g * 16) ^ rsw));
#pragma unroll
      for (int nj = 0; nj < 2; ++nj)
        bfr[nj] = *(const bf16x8*)(Bl + (wc * 32 + nj * 16 + l15) * 128 +
                                   ((ks * 64 + g * 16) ^ rsw));
#pragma unroll
      for (int mi = 0; mi < 4; ++mi)
#pragma unroll
        for (int nj = 0; nj < 2; ++nj)
          acc[mi][nj] = __builtin_amdgcn_mfma_f32_16x16x32_bf16(
              af[mi], bfr[nj], acc[mi][nj], 0, 0, 0);
    }
  }
  const int chunk = bx >> 3;               // 0=Q 1=K 2=V
  const int bb = m0 >> 11;
  const int hh = bx & 7;                   // head (block covers exactly one)
  if (chunk == 2) {
#pragma unroll
    for (int nj = 0; nj < 2; ++nj) {
      int dd = wc * 32 + nj * 16 + l15;
#pragma unroll
      for (int mi = 0; mi < 4; ++mi) {
        int ii0 = (m0 & (SEQ - 1)) + wr * 64 + mi * 16 + g * 4;
        union { unsigned short u[4]; ushort4 v; } pk;
#pragma unroll
        for (int r = 0; r < 4; ++r) pk.u[r] = bfbits(acc[mi][nj][r]);
        *(ushort4*)(Vt + ((size_t)(bb * HEADS + hh) * DHEAD + dd) * SEQ + ii0) = pk.v;
      }
    }
  } else {
    if (chunk == 1) {                      // fused key-bound: max|k| per (b,h)
      float kab = 0.f;
#pragma unroll
      for (int nj = 0; nj < 2; ++nj)
#pragma unroll
        for (int mi = 0; mi < 4; ++mi)
#pragma unroll
          for (int r = 0; r < 4; ++r) kab = fmaxf(kab, fabsf(acc[mi][nj][r]));
#pragma unroll
      for (int d = 1; d < 64; d <<= 1) kab = fmaxf(kab, __shfl_xor(kab, d));
      if (lane == 0)
        atomicMax(kmaxn + (bb * HEADS + hh), __float_as_uint(kab * 1.005f));
    }
    // repack 128x64 bf16 tile through LDS -> coalesced stores
    unsigned short* dst = (chunk == 0) ? Qbf : Kbf;
    const float sc = (chunk == 0) ? QSCALE_L2 : 1.f;
    __syncthreads();                       // Al reuse
#pragma unroll
    for (int nj = 0; nj < 2; ++nj) {
      int dd = wc * 32 + nj * 16 + l15;
#pragma unroll
      for (int mi = 0; mi < 4; ++mi) {
#pragma unroll
        for (int r = 0; r < 4; ++r) {
          int rowl = wr * 64 + mi * 16 + g * 4 + r;
          *(unsigned short*)(Al + rowl * 128 + ((dd * 2) ^ ((rowl & 7) << 4))) =
              bfbits(acc[mi][nj][r] * sc);
        }
      }
    }
    __syncthreads();
    const int rr = tid >> 1, hf = tid & 1;
    const int ii0 = (m0 & (SEQ - 1));
    unsigned short* gout =
        dst + ((size_t)(bb * HEADS + hh) * SEQ + ii0 + rr) * DHEAD + hf * 32;
    const int sw2 = (rr & 7) << 4;
#pragma unroll
    for (int q = 0; q < 4; ++q)
      *(int4*)(gout + q * 8) =
          *(const int4*)(Al + rr * 128 + ((hf * 64 + q * 16) ^ sw2));
  }
}

// ---------------- flash attention: split-KV x2, dbuf, in-reg P ---------------
// S^T = mfma(K,Q): lane (l15,g) holds P[q=l15][key=16j+4g+r]; exp2 with fixed
// bound B shared across splits -> partials directly summable. V layout:
// half-swapped store so ds_read_b64 fragments are bank-conflict-free.
__global__ __launch_bounds__(256) void attn_split(const unsigned short* __restrict__ Qbf,
                                                  const unsigned short* __restrict__ Kbf,
                                                  const unsigned short* __restrict__ Vt,
                                                  const float* __restrict__ maskf,
                                                  const unsigned* __restrict__ kmaxn,
                                                  unsigned short* __restrict__ Po,
                                                  float* __restrict__ LSUM) {
  __shared__ __align__(16) unsigned char Ks[16384];   // 2 x 8KB
  __shared__ __align__(16) unsigned char Vs[16384];

  const int tid = threadIdx.x;
  const int lane = tid & 63;
  const int w = tid >> 6;
  const int l15 = lane & 15, g = lane >> 4;

  int fid = blockIdx.x;
  int lid = (fid & 7) * 128 + (fid >> 3);  // bijective over 1024
  const int bh = lid >> 6;                 // 0..15
  const int rem = lid & 63;
  const int qb = rem >> 1;                 // 0..31
  const int half = rem & 1;
  const int bb = bh >> 3;

  const unsigned short* Qg = Qbf + ((size_t)bh * SEQ + qb * 64) * DHEAD;
  const unsigned short* Kg = Kbf + (size_t)bh * SEQ * DHEAD;
  const unsigned short* Vg = Vt  + (size_t)bh * DHEAD * SEQ;
  const float* mrow = maskf + bb * SEQ;

  bf16x8 qf0, qf1;
  {
    const unsigned char* qrow = (const unsigned char*)(Qg + (size_t)(w * 16 + l15) * DHEAD);
    qf0 = *(const bf16x8*)(qrow + g * 16);
    qf1 = *(const bf16x8*)(qrow + 64 + g * 16);
  }
  float Bx;
  {
    float qn2 = 0.f;
#pragma unroll
    for (int i = 0; i < 8; ++i) {
      float a = (float)qf0[i]; qn2 += a * a;
      float b = (float)qf1[i]; qn2 += b * b;
    }
    qn2 += __shfl_xor(qn2, 16);
    qn2 += __shfl_xor(qn2, 32);
    const float kabs = __uint_as_float(kmaxn[bh]);
    Bx = sqrtf(qn2) * 8.f * kabs;          // log2-units (Q pre-scaled)
  }

  f32x4 o[4] = {};
  float lsum = 0.f;

  const int sm = tid >> 2;
  const int sc = (tid & 3) * 32;
  const int ssw = (sm & 7) << 4;
  const int vswap = (sm >> 3) & 1;         // half-swap flag for V stores
  const int rsw = (l15 & 7) << 4;
  const int vsw = rsw | (((l15 >> 3) & 1) << 3);   // V-read swizzle (8B gran)
  const int kt0 = half * 16;

  int4 rk0, rk1, rv0, rv1;
  {
    const unsigned char* ksrc =
        (const unsigned char*)(Kg + (size_t)kt0 * 64 * DHEAD) + sm * 128 + sc;
    const unsigned char* vsrc =
        (const unsigned char*)(Vg + (size_t)sm * SEQ + kt0 * 64) + sc;
    rk0 = *(const int4*)(ksrc); rk1 = *(const int4*)(ksrc + 16);
    rv0 = *(const int4*)(vsrc); rv1 = *(const int4*)(vsrc + 16);
  }
  {
    *(int4*)(Ks + sm * 128 + ((sc)      ^ ssw)) = rk0;
    *(int4*)(Ks + sm * 128 + ((sc + 16) ^ ssw)) = rk1;
    int4 sv0 = vswap ? (int4){rv0.z, rv0.w, rv0.x, rv0.y} : rv0;
    int4 sv1 = vswap ? (int4){rv1.z, rv1.w, rv1.x, rv1.y} : rv1;
    *(int4*)(Vs + sm * 128 + ((sc)      ^ ssw)) = sv0;
    *(int4*)(Vs + sm * 128 + ((sc + 16) ^ ssw)) = sv1;
  }
  __syncthreads();

  for (int t = 0; t < 16; ++t) {
    const int kt = kt0 + t;
    const int co = (t & 1) << 13;          // current buffer byte offset
    const int no = co ^ 8192;              // next buffer
    float4 km[4];
#pragma unroll
    for (int j = 0; j < 4; ++j) km[j] = *(const float4*)(mrow + kt * 64 + 16 * j + 4 * g);
    if (t < 15) {                          // T14: issue next tile's loads now
      const unsigned char* ksrc =
          (const unsigned char*)(Kg + (size_t)(kt + 1) * 64 * DHEAD) + sm * 128 + sc;
      const unsigned char* vsrc =
          (const unsigned char*)(Vg + (size_t)sm * SEQ + (kt + 1) * 64) + sc;
      rk0 = *(const int4*)(ksrc); rk1 = *(const int4*)(ksrc + 16);
      rv0 = *(const int4*)(vsrc); rv1 = *(const int4*)(vsrc + 16);
    }

    // S^T = K · Q^T
    f32x4 s[4];
    __builtin_amdgcn_s_setprio(1);
#pragma unroll
    for (int j = 0; j < 4; ++j) {
      const unsigned char* krow = Ks + co + (16 * j + l15) * 128;
      bf16x8 kf0 = *(const bf16x8*)(krow + ((g * 16)      ^ rsw));
      bf16x8 kf1 = *(const bf16x8*)(krow + ((64 + g * 16) ^ rsw));
      f32x4 z = (f32x4){0.f, 0.f, 0.f, 0.f};
      z = __builtin_amdgcn_mfma_f32_16x16x32_bf16(kf0, qf0, z, 0, 0, 0);
      z = __builtin_amdgcn_mfma_f32_16x16x32_bf16(kf1, qf1, z, 0, 0, 0);
      s[j] = z;
    }
    __builtin_amdgcn_s_setprio(0);

    // p = exp2(s - Bx) * km ; pack to bf16x4 A-fragments in-register
    s16x4 pa[4];
#pragma unroll
    for (int j = 0; j < 4; ++j) {
      float p0 = EXP2F(s[j][0] - Bx) * km[j].x;
      float p1 = EXP2F(s[j][1] - Bx) * km[j].y;
      float p2 = EXP2F(s[j][2] - Bx) * km[j].z;
      float p3 = EXP2F(s[j][3] - Bx) * km[j].w;
      lsum += (p0 + p1) + (p2 + p3);
      union { uint2 u; s16x4 v; } pk;
      pk.u.x = cvtpk(p0, p1);
      pk.u.y = cvtpk(p2, p3);
      pa[j] = pk.v;
    }

    // O += P @ V via 16x16x16 (conflict-free b64 reads)
    __builtin_amdgcn_s_setprio(1);
#pragma unroll
    for (int dj = 0; dj < 4; ++dj) {
      const unsigned char* vrow = Vs + co + (16 * dj + l15) * 128;
#pragma unroll
      for (int j = 0; j < 4; ++j) {
        s16x4 vb = *(const s16x4*)(vrow + ((32 * j + 8 * g) ^ vsw));
        o[dj] = mfma16(pa[j], vb, o[dj]);
      }
    }
    __builtin_amdgcn_s_setprio(0);

    if (t < 15) {                          // stage next tile into other buffer
      *(int4*)(Ks + no + sm * 128 + ((sc)      ^ ssw)) = rk0;
      *(int4*)(Ks + no + sm * 128 + ((sc + 16) ^ ssw)) = rk1;
      int4 sv0 = vswap ? (int4){rv0.z, rv0.w, rv0.x, rv0.y} : rv0;
      int4 sv1 = vswap ? (int4){rv1.z, rv1.w, rv1.x, rv1.y} : rv1;
      *(int4*)(Vs + no + sm * 128 + ((sc)      ^ ssw)) = sv0;
      *(int4*)(Vs + no + sm * 128 + ((sc + 16) ^ ssw)) = sv1;
      __syncthreads();                     // single barrier per tile
    }
  }

  // epilogue: write unnormalized partial O + row-sum (shared B across splits)
#pragma unroll
  for (int r = 0; r < 4; ++r) {
    int row = qb * 64 + w * 16 + 4 * g + r;
    size_t base = (size_t)half * QKV_ELEMS + ((size_t)bh * SEQ + row) * DHEAD + l15;
    Po[base]      = bfbits(o[0][r]);
    Po[base + 16] = bfbits(o[1][r]);
    Po[base + 32] = bfbits(o[2][r]);
    Po[base + 48] = bfbits(o[3][r]);
  }
  lsum += __shfl_xor(lsum, 16);
  lsum += __shfl_xor(lsum, 32);
  if (g == 0) {
    int row = qb * 64 + w * 16 + l15;
    LSUM[half * BHS + bh * SEQ + row] = lsum;
  }
}

// ---------------- combine 2 partials (plain sum) + conv residual -> Obf ------
__global__ __launch_bounds__(256) void combine_conv(
    const unsigned short* __restrict__ Po, const float* __restrict__ LSUM,
    const unsigned short* __restrict__ Vt, const float* __restrict__ cw,
    unsigned short* __restrict__ Obf) {
  __shared__ float T[96][68];
  __shared__ float cwl[33];
  const int tid = threadIdx.x;
  const int bid = blockIdx.x;              // 512 = 16 bh x 32 n-chunks
  const int bh = bid >> 5;
  const int n0 = (bid & 31) * 64;
  const int hh = bh & 7;
  if (tid < 33) cwl[tid] = cw[hh * 33 + tid];
  for (int idx = tid; idx < 64 * 24; idx += 256) {
    int d = idx / 24, c4 = idx - (idx / 24) * 24;
    int nbase = n0 - 16 + c4 * 4;
    const unsigned short* src = Vt + ((size_t)bh * DHEAD + d) * SEQ;
#pragma unroll
    for (int q = 0; q < 4; ++q) {
      int n = nbase + q;
      T[c4 * 4 + q][d] = (n >= 0 && n < SEQ) ? bf2f(src[n]) : 0.f;
    }
  }
  __syncthreads();
#pragma unroll
  for (int p = 0; p < 4; ++p) {
    int n = (tid >> 4) + p * 16;           // 0..63
    int d4 = tid & 15;
    int row = bh * SEQ + n0 + n;
    float tot = 0.f;
#pragma unroll
    for (int q = 0; q < NSPLIT; ++q) tot += LSUM[q * BHS + row];
    float inv = (tot > 0.f) ? 1.f / tot : 0.f;
    float o0 = 0.f, o1 = 0.f, o2 = 0.f, o3 = 0.f;
#pragma unroll
    for (int q = 0; q < NSPLIT; ++q) {
      ushort4 a = *(const ushort4*)(Po + (size_t)q * QKV_ELEMS + (size_t)row * DHEAD + d4 * 4);
      o0 += bf2f(a.x); o1 += bf2f(a.y);
      o2 += bf2f(a.z); o3 += bf2f(a.w);
    }
    o0 *= inv; o1 *= inv; o2 *= inv; o3 *= inv;
#pragma unroll
    for (int t = 0; t < 33; ++t) {
      float wv = cwl[t];
      float4 tv = *(const float4*)&T[n + t][d4 * 4];
      o0 += wv * tv.x; o1 += wv * tv.y; o2 += wv * tv.z; o3 += wv * tv.w;
    }
    union { unsigned short u[4]; ushort4 v; } pk;
    pk.u[0] = bfbits(o0); pk.u[1] = bfbits(o1);
    pk.u[2] = bfbits(o2); pk.u[3] = bfbits(o3);
    *(ushort4*)(Obf + (size_t)row * DHEAD + d4 * 4) = pk.v;
  }
}

// ---------------- out GEMM (MFMA): Obf bf16 gather-A, 64x64 tiles ------------
__global__ __launch_bounds__(256) void gemm_out_mfma(
    const unsigned short* __restrict__ Obf, const unsigned short* __restrict__ Wt,
    const float* __restrict__ bias, const float* __restrict__ maskf,
    float* __restrict__ out) {
  __shared__ __align__(16) unsigned char Al[64 * 128];
  __shared__ __align__(16) unsigned char Bl[64 * 128];
  const int tid = threadIdx.x;
  const int lane = tid & 63;
  const int w = tid >> 6;
  const int l15 = lane & 15, g = lane >> 4;
  const int wr = w >> 1, wc = w & 1;
  int bid = blockIdx.x;                    // 512 blocks
  int lid = (bid & 7) * 64 + (bid >> 3);
  int by = lid >> 3, bx = lid & 7;         // by 0..63, bx 0..7
  const int m0 = by * 64, n0 = bx * 64;
  const int bb = m0 >> 11;
  const int ii0 = m0 & (SEQ - 1);

  f32x4 acc[2][2] = {};
  const int srow = tid >> 3, scg = tid & 7;
  const int rsw = (l15 & 7) << 4;

  for (int k0 = 0; k0 < DIMM; k0 += 64) {
    const int hh = k0 >> 6;
    __syncthreads();
#pragma unroll
    for (int it = 0; it < 2; ++it) {
      int row = srow + it * 32;
      int sw = (row & 7) << 4;
      *(int4*)(Al + row * 128 + ((scg * 16) ^ sw)) =
          *(const int4*)(Obf + ((size_t)(bb * HEADS + hh) * SEQ + ii0 + row) * DHEAD + scg * 8);
      *(int4*)(Bl + row * 128 + ((scg * 16) ^ sw)) =
          *(const int4*)(Wt + (size_t)(n0 + row) * DIMM + k0 + scg * 8);
    }
    __syncthreads();
#pragma unroll
    for (int ks = 0; ks < 2; ++ks) {
      bf16x8 af[2], bfr[2];
#pragma unroll
      for (int mi = 0; mi < 2; ++mi)
        af[mi] = *(const bf16x8*)(Al + (wr * 32 + mi * 16 + l15) * 128 +
                                  ((ks * 64 + g * 16) ^ rsw));
#pragma unroll
      for (int nj = 0; nj < 2; ++nj)
        bfr[nj] = *(const bf16x8*)(Bl + (wc * 32 + nj * 16 + l15) * 128 +
                                   ((ks * 64 + g * 16) ^ rsw));
#pragma unroll
      for (int mi = 0; mi < 2; ++mi)
#pragma unroll
        for (int nj = 0; nj < 2; ++nj)
          acc[mi][nj] = __builtin_amdgcn_mfma_f32_16x16x32_bf16(
              af[mi], bfr[nj], acc[mi][nj], 0, 0, 0);
    }
  }
#pragma unroll
  for (int nj = 0; nj < 2; ++nj) {
    int col = n0 + wc * 32 + nj * 16 + l15;
    float bcol = bias[col];
#pragma unroll
    for (int mi = 0; mi < 2; ++mi) {
#pragma unroll
      for (int r = 0; r < 4; ++r) {
        int m = m0 + wr * 32 + mi * 16 + g * 4 + r;
        out[(size_t)m * DIMM + col] = (acc[mi][nj][r] + bcol) * maskf[m];
      }
    }
  }
}

extern "C" void kernel_launch(void* const* d_in, const int* in_sizes, int n_in,
                              void* d_out, int out_size, void* d_ws, size_t ws_size,
                              hipStream_t stream) {
  const float* x     = (const float*)d_in[0];
  const void*  mask  = d_in[1];
  const float* Wqkv  = (const float*)d_in[2];
  const float* Wout  = (const float*)d_in[3];
  const float* bout  = (const float*)d_in[4];
  const float* convw = (const float*)d_in[5];
  float* out = (float*)d_out;

  float* maskf = (float*)d_ws;
  unsigned* kmaxn = (unsigned*)(maskf + 4096);           // 16 used, pad 64
  unsigned short* Qbf = (unsigned short*)(kmaxn + 64);
  unsigned short* Kbf = Qbf + QKV_ELEMS;
  unsigned short* Vt  = Kbf + QKV_ELEMS;
  unsigned short* Po  = Vt + QKV_ELEMS;                  // NSPLIT partials
  float* LSUM         = (float*)(Po + NSPLIT * QKV_ELEMS);
  unsigned short* Obf = (unsigned short*)(LSUM + NSPLIT * BHS);
  unsigned short* Wtq = Obf + QKV_ELEMS;                 // 1536*512
  unsigned short* Wto = Wtq + (size_t)NQKV * DIMM;       // 512*512
  unsigned short* Xbf = Wto + (size_t)DIMM * DIMM;       // 4096*512

  prep_all<<<1281, 256, 0, stream>>>(x, mask, Wqkv, Wout, Xbf, maskf, Wtq, Wto, kmaxn);
  gemm_qkv_mfma<<<768, 256, 0, stream>>>(Xbf, Wtq, Qbf, Kbf, Vt, kmaxn);
  attn_split<<<1024, 256, 0, stream>>>(Qbf, Kbf, Vt, maskf, kmaxn, Po, LSUM);
  combine_conv<<<512, 256, 0, stream>>>(Po, LSUM, Vt, convw, Obf);
  gemm_out_mfma<<<512, 256, 0, stream>>>(Obf, Wto, bout, maskf, out);
}